// Round 1
// 696.270 us; speedup vs baseline: 1.6229x; 1.6229x over previous
//
#include <hip/hip_runtime.h>

#define LSEQ 384
#define DIM 128
#define NHEADS 4
#define HDIM 16

typedef __attribute__((ext_vector_type(8))) short bf16x8;
typedef __attribute__((ext_vector_type(4))) short bf16x4;
typedef __attribute__((ext_vector_type(4))) float f32x4;

#define MFMA32(A,B,C) __builtin_amdgcn_mfma_f32_16x16x32_bf16(A,B,C,0,0,0)

#if __has_builtin(__builtin_amdgcn_mfma_f32_16x16x16bf16_1k)
#define HAVE_MFMA16 1
#else
#define HAVE_MFMA16 0
#endif

// ---------- helpers ----------
__device__ __forceinline__ float bf2f_lo(unsigned int u) { return __uint_as_float(u << 16); }
__device__ __forceinline__ float bf2f_hi(unsigned int u) { return __uint_as_float(u & 0xFFFF0000u); }
__device__ __forceinline__ float bf2f_s(unsigned short s) { return __uint_as_float(((unsigned int)s) << 16); }
__device__ __forceinline__ unsigned short f2bf(float f) {
    unsigned int u = __float_as_uint(f);
    u += 0x7FFFu + ((u >> 16) & 1u);   // round-to-nearest-even
    return (unsigned short)(u >> 16);
}
// pack two f32 -> one dword of 2x bf16 (RTNE), single instruction (T12 recipe)
__device__ __forceinline__ unsigned int pkbf(float a, float b) {
    unsigned int r;
    asm("v_cvt_pk_bf16_f32 %0, %1, %2" : "=v"(r) : "v"(a), "v"(b));
    return r;
}
__device__ __forceinline__ float ex2(float x) {
#if __has_builtin(__builtin_amdgcn_exp2f)
    return __builtin_amdgcn_exp2f(x);
#else
    return exp2f(x);
#endif
}
__device__ __forceinline__ float wred_sum(float v) {
#pragma unroll
    for (int off = 32; off > 0; off >>= 1) v += __shfl_xor(v, off, 64);
    return v;
}
__device__ __forceinline__ void stval(float* p, float v) { *p = v; }
__device__ __forceinline__ void stval(unsigned short* p, float v) { *p = f2bf(v); }
__device__ __forceinline__ float2 ldpair(const float* A, long e2) {
    return *(const float2*)(A + 2 * e2);
}
__device__ __forceinline__ float2 ldpair(const unsigned short* A, long e2) {
    unsigned int u = *(const unsigned int*)(A + 2 * e2);
    return make_float2(bf2f_lo(u), bf2f_hi(u));
}

// ================= qkvg: LN + qkv/gate projection via MFMA =================
// Writes q*(0.25*log2e), k, v, sigmoid(gate) as bf16 into [b][h][n][16] layout.
#define XSTR 138   // LDS row stride in bf16
__global__ __launch_bounds__(256, 2) void qkvg_kernel(
    const float* __restrict__ x, long sb, long sn,
    const float* __restrict__ ln_g, const float* __restrict__ ln_b,
    const float* __restrict__ w_qkv, const float* __restrict__ w_gate,
    const float* __restrict__ b_gate,
    unsigned short* __restrict__ qws, unsigned short* __restrict__ kws,
    unsigned short* __restrict__ vws, unsigned short* __restrict__ gws)
{
    const int b   = blockIdx.x;
    const int q4  = blockIdx.y;          // token quarter (96 tokens each)
    const int tid = threadIdx.x, wave = tid >> 6, lane = tid & 63;
    const int jl  = lane & 15, g = lane >> 4;

    __shared__ __align__(16) unsigned short xn[96 * XSTR];
    __shared__ __align__(16) unsigned short xr[96 * XSTR];

    // ---- weight B-frags (16x16x32): wave owns n-tiles wave*4 .. wave*4+3
    bf16x8 wfrag[4][4];
    float gbias[4];
#pragma unroll
    for (int t = 0; t < 4; ++t) {
        int nt = wave * 4 + t;
        int c  = nt * 16 + jl;
        const float* wr;
        float scale;
        if (nt < 12) { wr = w_qkv + (long)c * DIM; scale = (nt < 4) ? 0.36067376022224085f : 1.0f; gbias[t] = 0.f; }
        else         { wr = w_gate + (long)(c - 192) * DIM; scale = 1.0f; gbias[t] = b_gate[c - 192]; }
#pragma unroll
        for (int ks = 0; ks < 4; ++ks) {
            int k0 = ks * 32 + g * 8;
            float4 w0 = *(const float4*)(wr + k0);
            float4 w1 = *(const float4*)(wr + k0 + 4);
            union { unsigned int u[4]; bf16x8 v; } f;
            f.u[0] = pkbf(w0.x * scale, w0.y * scale);
            f.u[1] = pkbf(w0.z * scale, w0.w * scale);
            f.u[2] = pkbf(w1.x * scale, w1.y * scale);
            f.u[3] = pkbf(w1.z * scale, w1.w * scale);
            wfrag[t][ks] = f.v;
        }
    }

    // ---- LayerNorm: 24 tokens per wave, stage normed + raw bf16 into LDS
    const float* xbase = x + (long)b * sb + (long)(q4 * 96) * sn;
    const float lg0 = ln_g[lane], lg1 = ln_g[lane + 64];
    const float lb0 = ln_b[lane], lb1 = ln_b[lane + 64];
    for (int i = 0; i < 24; ++i) {
        int tk = wave * 24 + i;
        const float* xp = xbase + (long)tk * sn;
        float x0 = xp[lane], x1 = xp[lane + 64];
        float s  = wred_sum(x0 + x1);
        float sq = wred_sum(x0 * x0 + x1 * x1);
        float mean = s * (1.f / 128.f);
        float var  = sq * (1.f / 128.f) - mean * mean;
        float inv  = rsqrtf(var + 1e-5f);
        xn[tk * XSTR + lane]      = f2bf((x0 - mean) * inv * lg0 + lb0);
        xn[tk * XSTR + lane + 64] = f2bf((x1 - mean) * inv * lg1 + lb1);
        xr[tk * XSTR + lane]      = f2bf(x0);
        xr[tk * XSTR + lane + 64] = f2bf(x1);
    }
    __syncthreads();

    // ---- GEMM: 6 m-tiles x 4 n-tiles x 4 k-steps (16x16x32)
    const unsigned int* a32 = (const unsigned int*)((wave == 3) ? xr : xn);
    for (int mt = 0; mt < 6; ++mt) {
        bf16x8 af[4];
#pragma unroll
        for (int ks = 0; ks < 4; ++ks) {
            int adw = (mt * 16 + jl) * (XSTR / 2) + ks * 16 + g * 4;
            union { unsigned int u[4]; bf16x8 v; } cv;
            cv.u[0] = a32[adw]; cv.u[1] = a32[adw + 1];
            cv.u[2] = a32[adw + 2]; cv.u[3] = a32[adw + 3];
            af[ks] = cv.v;
        }
#pragma unroll
        for (int t = 0; t < 4; ++t) {
            int nt = wave * 4 + t;
            f32x4 acc = {0.f, 0.f, 0.f, 0.f};
#pragma unroll
            for (int ks = 0; ks < 4; ++ks) acc = MFMA32(af[ks], wfrag[t][ks], acc);
            int mat = nt >> 2, hh = nt & 3;
            unsigned short* outp = (mat == 0) ? qws : (mat == 1) ? kws : (mat == 2) ? vws : gws;
            long base = (((long)b * NHEADS + hh) * LSEQ + q4 * 96 + mt * 16 + g * 4) * HDIM + jl;
            if (mat == 3) {
#pragma unroll
                for (int r = 0; r < 4; ++r) {
                    float v = 1.f / (1.f + __expf(-(acc[r] + gbias[t])));
                    outp[base + r * HDIM] = f2bf(v);
                }
            } else {
#pragma unroll
                for (int r = 0; r < 4; ++r) outp[base + r * HDIM] = f2bf(acc[r]);
            }
        }
    }
}

// ================= attention core: S=QK^T, softmax over j, O=P^T V, gate ===
// Fragment loader for S-MFMAs. HDIM=16, so with the K=16 MFMA every lane is
// active (b64 reads); fallback path zero-pads K=32 (only g<2 lanes carry data).
#if HAVE_MFMA16
typedef bf16x4 sfrag_t;
#define SMFMA(A,B,C) __builtin_amdgcn_mfma_f32_16x16x16bf16_1k(A,B,C,0,0,0)
__device__ __forceinline__ sfrag_t ldfrag(const unsigned int* b32, int row, int g) {
    union { unsigned int u[2]; bf16x4 v; } c;
    const unsigned int* p = b32 + row * 12 + g * 2;
    c.u[0] = p[0]; c.u[1] = p[1];
    return c.v;
}
#else
typedef bf16x8 sfrag_t;
#define SMFMA(A,B,C) MFMA32(A,B,C)
__device__ __forceinline__ sfrag_t ldfrag(const unsigned int* b32, int row, int g) {
    union { unsigned int u[4]; bf16x8 v; } c;
    if (g < 2) {
        uint4 x = *(const uint4*)(b32 + row * 12 + g * 4);
        c.u[0] = x.x; c.u[1] = x.y; c.u[2] = x.z; c.u[3] = x.w;
    } else {
        c.u[0] = c.u[1] = c.u[2] = c.u[3] = 0;
    }
    return c.v;
}
#endif

__global__ __launch_bounds__(256, 2) void attn_core_kernel(
    const unsigned short* __restrict__ qws, const unsigned short* __restrict__ kws,
    const unsigned short* __restrict__ vws, const unsigned short* __restrict__ gws,
    float* __restrict__ attn_out)
{
    const int b = blockIdx.x, h = blockIdx.y;
    const int tid = threadIdx.x, wave = tid >> 6, lane = tid & 63;
    const int jl  = lane & 15, g = lane >> 4;

    __shared__ __align__(16) unsigned short qs[LSEQ * 24];   // 18432 B
    __shared__ __align__(16) unsigned short ks[LSEQ * 24];   // 18432 B
    __shared__ __align__(16) unsigned short vs[LSEQ * 18];   // 13824 B
    __shared__ float linv[LSEQ];                             //  1536 B  (total 52224 -> 3 blocks/CU)

    const long goff = ((long)b * NHEADS + h) * (LSEQ * HDIM);

    // ---- stage q,k (stride 24), v (stride 18); gate stays in global (no reuse)
    {
        const uint4* gq = (const uint4*)(qws + goff);
        const uint4* gk = (const uint4*)(kws + goff);
        unsigned int* q32s = (unsigned int*)qs;
        unsigned int* k32s = (unsigned int*)ks;
        for (int e = tid; e < 768; e += 256) {
            int tk = e >> 1, hf = e & 1;
            *(uint4*)(q32s + tk * 12 + hf * 4) = gq[e];
            *(uint4*)(k32s + tk * 12 + hf * 4) = gk[e];
        }
        const unsigned int* gv = (const unsigned int*)(vws + goff);
        unsigned int* v32 = (unsigned int*)vs;
        for (int e = tid; e < 3072; e += 256) {
            int tk = e >> 3, j = e & 7;
            v32[tk * 9 + j] = gv[e];
        }
    }
    __syncthreads();

    const unsigned int* q32 = (const unsigned int*)qs;
    const unsigned int* k32 = (const unsigned int*)ks;

    // own-tile frags (tile = wave*6 + t)
    sfrag_t Qo[6], Ko[6];
#pragma unroll
    for (int t = 0; t < 6; ++t) {
        Qo[t] = ldfrag(q32, (wave * 6 + t) * 16 + jl, g);
        Ko[t] = ldfrag(k32, (wave * 6 + t) * 16 + jl, g);
    }

    const f32x4 fz = {0.f, 0.f, 0.f, 0.f};

    // ---- pass 1: l_i = sum_j 2^(s'_ij); scores pre-scaled via q by 0.25*log2e
    // Per-lane f32 partial over this lane's 8 j's per u-step; cross-lane reduce
    // over the 4 g-groups at the end (i = tile*16 + jl).
    for (int t = 0; t < 6; ++t) {
        float lsum = 0.f;
        for (int u = 0; u < 12; ++u) {
            sfrag_t c0 = ldfrag(k32, 32 * u + jl, g);
            sfrag_t c1 = ldfrag(k32, 32 * u + 16 + jl, g);
            f32x4 s0 = SMFMA(c0, Qo[t], fz);
            f32x4 s1 = SMFMA(c1, Qo[t], fz);
            float e0 = ex2(s0[0]) + ex2(s0[1]);
            float e1 = ex2(s0[2]) + ex2(s0[3]);
            float e2 = ex2(s1[0]) + ex2(s1[1]);
            float e3 = ex2(s1[2]) + ex2(s1[3]);
            lsum += (e0 + e1) + (e2 + e3);
        }
        lsum += __shfl_xor(lsum, 16, 64);
        lsum += __shfl_xor(lsum, 32, 64);
        if (lane < 16) linv[(wave * 6 + t) * 16 + jl] = 1.f / lsum;
    }
    __syncthreads();

    // ---- V-hat B-frags with the tau permutation: slot (g,jj) -> token
    bf16x8 VB8[12];
#pragma unroll
    for (int u = 0; u < 12; ++u) {
        union { unsigned int w[4]; bf16x8 v; } vv;
#pragma unroll
        for (int p = 0; p < 4; ++p) {
            int t0 = 32 * u + ((p < 2) ? (g * 4 + 2 * p) : (16 + g * 4 + 2 * (p - 2)));
            float a  = bf2f_s(vs[t0 * 18 + jl])       * linv[t0];
            float bb = bf2f_s(vs[(t0 + 1) * 18 + jl]) * linv[t0 + 1];
            vv.w[p] = pkbf(a, bb);
        }
        VB8[u] = vv.v;
    }

    // ---- pass 2: O[j][d] = sum_i 2^(s'_ij) * vhat[i][d]; gate & store
    for (int t = 0; t < 6; ++t) {
        // prefetch the 4 gate scalars for this tile (hide HBM latency under u-loop)
        const unsigned short* gp = gws + goff + (((wave * 6 + t) * 16 + g * 4) * 16 + jl);
        unsigned short gv0 = gp[0], gv1 = gp[16], gv2 = gp[32], gv3 = gp[48];

        f32x4 o = fz;
        for (int u = 0; u < 12; ++u) {
            sfrag_t c0 = ldfrag(q32, 32 * u + jl, g);
            sfrag_t c1 = ldfrag(q32, 32 * u + 16 + jl, g);
            f32x4 s0 = SMFMA(c0, Ko[t], fz);
            f32x4 s1 = SMFMA(c1, Ko[t], fz);
            union { unsigned int w[4]; bf16x8 v; } pf;
            pf.w[0] = pkbf(ex2(s0[0]), ex2(s0[1]));
            pf.w[1] = pkbf(ex2(s0[2]), ex2(s0[3]));
            pf.w[2] = pkbf(ex2(s1[0]), ex2(s1[1]));
            pf.w[3] = pkbf(ex2(s1[2]), ex2(s1[3]));
            o = MFMA32(pf.v, VB8[u], o);
        }
        const unsigned short gv[4] = { gv0, gv1, gv2, gv3 };
#pragma unroll
        for (int r = 0; r < 4; ++r) {
            int jrow = (wave * 6 + t) * 16 + g * 4 + r;
            attn_out[((long)b * LSEQ + jrow) * 64 + h * HDIM + jl] = o[r] * bf2f_s(gv[r]);
        }
    }
}

// ========== MFMA projection: out[t,c] = R[t,c] + bias[c] + sum_k act(A[t,k])*W[c,k] ==========
// Block: 96 tokens x N cols (N = NT*64). Wave owns n-tiles wave*NT..wave*NT+NT-1.
// token t -> (i0 = t/384, j0 = t%384); 96 | 384 so i0 is block-constant.
template <int K, int NT, typename AT, typename OT, int ACT>
__global__ __launch_bounds__(256, 2) void mproj_kernel(
    const AT* __restrict__ A,
    const float* __restrict__ W, const float* __restrict__ Bv,
    const float* R, long rs0, long rs1,
    OT* out, long os0, long os1)
{
    constexpr int KS = K / 32;        // MFMA k-steps
    constexpr int RS = K / 2 + 4;     // LDS row stride in dwords (== 4 mod 32: 2-way max)
    const int tid = threadIdx.x, wave = tid >> 6, lane = tid & 63;
    const int jl = lane & 15, g = lane >> 4;

    __shared__ __align__(16) unsigned int abuf[96 * RS];

    // ---- weight B-frags + bias (per-lane col = nt*16+jl)
    bf16x8 wfrag[NT][KS];
    float bias[NT];
#pragma unroll
    for (int t = 0; t < NT; ++t) {
        int c = (wave * NT + t) * 16 + jl;
        const float* wr = W + (long)c * K;
        bias[t] = Bv[c];
#pragma unroll
        for (int ks = 0; ks < KS; ++ks) {
            int k0 = ks * 32 + g * 8;
            float4 w0 = *(const float4*)(wr + k0);
            float4 w1 = *(const float4*)(wr + k0 + 4);
            union { unsigned int u[4]; bf16x8 v; } f;
            f.u[0] = pkbf(w0.x, w0.y);
            f.u[1] = pkbf(w0.z, w0.w);
            f.u[2] = pkbf(w1.x, w1.y);
            f.u[3] = pkbf(w1.z, w1.w);
            wfrag[t][ks] = f.v;
        }
    }

    // ---- stage act(A) as bf16 into LDS
    const long t0 = (long)blockIdx.x * 96;
    for (int e = tid; e < 96 * (K / 2); e += 256) {
        int row = e / (K / 2), cp = e % (K / 2);
        float2 a = ldpair(A, t0 * (K / 2) + e);
        if (ACT) {
            a.x = a.x / (1.f + __expf(-a.x));
            a.y = a.y / (1.f + __expf(-a.y));
        }
        abuf[row * RS + cp] = pkbf(a.x, a.y);
    }
    __syncthreads();

    const int i0 = blockIdx.x >> 2;
    const int j0b = (blockIdx.x & 3) * 96;

    for (int mt = 0; mt < 6; ++mt) {
        bf16x8 af[KS];
#pragma unroll
        for (int ks = 0; ks < KS; ++ks) {
            int adw = (mt * 16 + jl) * RS + ks * 16 + g * 4;
            uint4 x = *(const uint4*)(abuf + adw);
            union { unsigned int u[4]; bf16x8 v; } cv;
            cv.u[0] = x.x; cv.u[1] = x.y; cv.u[2] = x.z; cv.u[3] = x.w;
            af[ks] = cv.v;
        }
#pragma unroll
        for (int t = 0; t < NT; ++t) {
            f32x4 acc = {0.f, 0.f, 0.f, 0.f};
#pragma unroll
            for (int ks = 0; ks < KS; ++ks) acc = MFMA32(af[ks], wfrag[t][ks], acc);
            const long co = (wave * NT + t) * 16 + jl;
#pragma unroll
            for (int r = 0; r < 4; ++r) {
                int j0 = j0b + mt * 16 + g * 4 + r;
                float val = acc[r] + bias[t];
                if (R) val += R[(long)i0 * rs0 + (long)j0 * rs1 + co];
                stval(&out[(long)i0 * os0 + (long)j0 * os1 + co], val);
            }
        }
    }
}

// ---------- launch ----------
extern "C" void kernel_launch(void* const* d_in, const int* in_sizes, int n_in,
                              void* d_out, int out_size, void* d_ws, size_t ws_size,
                              hipStream_t stream)
{
    const float* edge     = (const float*)d_in[0];
    const float* r_ln_g   = (const float*)d_in[1];
    const float* r_ln_b   = (const float*)d_in[2];
    const float* r_qkv_w  = (const float*)d_in[3];
    const float* r_gate_w = (const float*)d_in[4];
    const float* r_gate_b = (const float*)d_in[5];
    const float* r_fin_w  = (const float*)d_in[6];
    const float* r_fin_b  = (const float*)d_in[7];
    const float* c_ln_g   = (const float*)d_in[8];
    const float* c_ln_b   = (const float*)d_in[9];
    const float* c_qkv_w  = (const float*)d_in[10];
    const float* c_gate_w = (const float*)d_in[11];
    const float* c_gate_b = (const float*)d_in[12];
    const float* c_fin_w  = (const float*)d_in[13];
    const float* c_fin_b  = (const float*)d_in[14];
    const float* ff_w1    = (const float*)d_in[15];
    const float* ff_b1    = (const float*)d_in[16];
    const float* ff_w2    = (const float*)d_in[17];
    const float* ff_b2    = (const float*)d_in[18];

    char* ws = (char*)d_ws;
    // region A (75,497,472 B): qkvg buffers during attention; hbuf during FF
    unsigned short* qb = (unsigned short*)ws;
    unsigned short* kb = qb + 9437184;
    unsigned short* vb = qb + 2 * 9437184;
    unsigned short* gb = qb + 3 * 9437184;
    unsigned short* hbuf = (unsigned short*)ws;                 // reuse A in FF phase
    float* attn = (float*)(ws + 75497472);                      // 37,748,736 B
    float* y    = (float*)(ws + 75497472 + 37748736);           // 75,497,472 B

    const long LD = 49152; // 384*128

    // ---- row attention
    qkvg_kernel<<<dim3(LSEQ, 4), 256, 0, stream>>>(
        edge, LD, 128, r_ln_g, r_ln_b, r_qkv_w, r_gate_w, r_gate_b, qb, kb, vb, gb);
    attn_core_kernel<<<dim3(LSEQ, NHEADS), 256, 0, stream>>>(qb, kb, vb, gb, attn);
    mproj_kernel<64, 2, float, float, 0><<<1536, 256, 0, stream>>>(
        attn, r_fin_w, r_fin_b, edge, LD, 128, y, LD, 128);

    // ---- column attention (x viewed transposed via strides)
    qkvg_kernel<<<dim3(LSEQ, 4), 256, 0, stream>>>(
        y, 128, LD, c_ln_g, c_ln_b, c_qkv_w, c_gate_w, c_gate_b, qb, kb, vb, gb);
    attn_core_kernel<<<dim3(LSEQ, NHEADS), 256, 0, stream>>>(qb, kb, vb, gb, attn);
    mproj_kernel<64, 2, float, float, 0><<<1536, 256, 0, stream>>>(
        attn, c_fin_w, c_fin_b, y, 128, LD, y, 128, LD);

    // ---- feed-forward
    mproj_kernel<128, 4, float, unsigned short, 1><<<1536, 256, 0, stream>>>(
        y, ff_w1, ff_b1, nullptr, 0, 0, hbuf, 98304, 256);
    mproj_kernel<256, 2, unsigned short, float, 1><<<1536, 256, 0, stream>>>(
        hbuf, ff_w2, ff_b2, y, LD, 128, (float*)d_out, LD, 128);
}

// Round 2
// 606.253 us; speedup vs baseline: 1.8638x; 1.1485x over previous
//
#include <hip/hip_runtime.h>

#define LSEQ 384
#define DIM 128
#define NHEADS 4
#define HDIM 16

typedef __attribute__((ext_vector_type(8))) short bf16x8;
typedef __attribute__((ext_vector_type(4))) short bf16x4;
typedef __attribute__((ext_vector_type(4))) float f32x4;

#define MFMA32(A,B,C) __builtin_amdgcn_mfma_f32_16x16x32_bf16(A,B,C,0,0,0)

#if __has_builtin(__builtin_amdgcn_mfma_f32_16x16x16bf16_1k)
#define HAVE_MFMA16 1
#else
#define HAVE_MFMA16 0
#endif

// ---------- helpers ----------
__device__ __forceinline__ float bf2f_lo(unsigned int u) { return __uint_as_float(u << 16); }
__device__ __forceinline__ float bf2f_hi(unsigned int u) { return __uint_as_float(u & 0xFFFF0000u); }
__device__ __forceinline__ float bf2f_s(unsigned short s) { return __uint_as_float(((unsigned int)s) << 16); }
__device__ __forceinline__ unsigned short f2bf(float f) {
    unsigned int u = __float_as_uint(f);
    u += 0x7FFFu + ((u >> 16) & 1u);   // round-to-nearest-even
    return (unsigned short)(u >> 16);
}
// pack two f32 -> one dword of 2x bf16 (RTNE), single instruction (T12 recipe)
__device__ __forceinline__ unsigned int pkbf(float a, float b) {
    unsigned int r;
    asm("v_cvt_pk_bf16_f32 %0, %1, %2" : "=v"(r) : "v"(a), "v"(b));
    return r;
}
__device__ __forceinline__ float ex2(float x) {
#if __has_builtin(__builtin_amdgcn_exp2f)
    return __builtin_amdgcn_exp2f(x);
#else
    return exp2f(x);
#endif
}
__device__ __forceinline__ float frcp(float x) {
#if __has_builtin(__builtin_amdgcn_rcpf)
    return __builtin_amdgcn_rcpf(x);
#else
    return 1.f / x;
#endif
}
__device__ __forceinline__ float fsigm(float x) {      // sigmoid(x) = 1/(1+2^(-x*log2e))
    return frcp(1.f + ex2(-1.44269504088896341f * x));
}
__device__ __forceinline__ float fsilu(float x) { return x * fsigm(x); }
__device__ __forceinline__ float wred_sum(float v) {
#pragma unroll
    for (int off = 32; off > 0; off >>= 1) v += __shfl_xor(v, off, 64);
    return v;
}

// ================= qkvg: LN + qkv/gate projection via MFMA =================
// Writes q*(0.25*log2e), k, v, sigmoid(gate) as bf16 into [b][h][n][16] layout.
// GEMM uses swapped operands: D[c][token] so each thread holds 4 consecutive
// feature dims of one token -> coalesced uint2 (4x bf16) stores.
#define XSTR 138   // LDS row stride in bf16
__global__ __launch_bounds__(256, 2) void qkvg_kernel(
    const float* __restrict__ x, long sb, long sn,
    const float* __restrict__ ln_g, const float* __restrict__ ln_b,
    const float* __restrict__ w_qkv, const float* __restrict__ w_gate,
    const float* __restrict__ b_gate,
    unsigned short* __restrict__ qws, unsigned short* __restrict__ kws,
    unsigned short* __restrict__ vws, unsigned short* __restrict__ gws)
{
    const int b   = blockIdx.x;
    const int q4  = blockIdx.y;          // token quarter (96 tokens each)
    const int tid = threadIdx.x, wave = tid >> 6, lane = tid & 63;
    const int jl  = lane & 15, g = lane >> 4;

    __shared__ __align__(16) unsigned short xn[96 * XSTR];
    __shared__ __align__(16) unsigned short xr[96 * XSTR];

    // ---- weight B-frags (16x16x32): wave owns n-tiles wave*4 .. wave*4+3
    bf16x8 wfrag[4][4];
#pragma unroll
    for (int t = 0; t < 4; ++t) {
        int nt = wave * 4 + t;
        int c  = nt * 16 + jl;
        const float* wr;
        float scale;
        if (nt < 12) { wr = w_qkv + (long)c * DIM; scale = (nt < 4) ? 0.36067376022224085f : 1.0f; }
        else         { wr = w_gate + (long)(c - 192) * DIM; scale = 1.0f; }
#pragma unroll
        for (int ks = 0; ks < 4; ++ks) {
            int k0 = ks * 32 + g * 8;
            float4 w0 = *(const float4*)(wr + k0);
            float4 w1 = *(const float4*)(wr + k0 + 4);
            union { unsigned int u[4]; bf16x8 v; } f;
            f.u[0] = pkbf(w0.x * scale, w0.y * scale);
            f.u[1] = pkbf(w0.z * scale, w0.w * scale);
            f.u[2] = pkbf(w1.x * scale, w1.y * scale);
            f.u[3] = pkbf(w1.z * scale, w1.w * scale);
            wfrag[t][ks] = f.v;
        }
    }
    // gate bias: per (t, g, r) now (swapped output): only wave 3 needs it
    float4 gb4[4];
    if (wave == 3) {
#pragma unroll
        for (int t = 0; t < 4; ++t) gb4[t] = *(const float4*)(b_gate + t * 16 + g * 4);
    }

    // ---- LayerNorm: 24 tokens per wave, stage normed + raw bf16 into LDS
    const float* xbase = x + (long)b * sb + (long)(q4 * 96) * sn;
    const float lg0 = ln_g[lane], lg1 = ln_g[lane + 64];
    const float lb0 = ln_b[lane], lb1 = ln_b[lane + 64];
    for (int i = 0; i < 24; ++i) {
        int tk = wave * 24 + i;
        const float* xp = xbase + (long)tk * sn;
        float x0 = xp[lane], x1 = xp[lane + 64];
        float s  = wred_sum(x0 + x1);
        float sq = wred_sum(x0 * x0 + x1 * x1);
        float mean = s * (1.f / 128.f);
        float var  = sq * (1.f / 128.f) - mean * mean;
        float inv  = rsqrtf(var + 1e-5f);
        xn[tk * XSTR + lane]      = f2bf((x0 - mean) * inv * lg0 + lb0);
        xn[tk * XSTR + lane + 64] = f2bf((x1 - mean) * inv * lg1 + lb1);
        xr[tk * XSTR + lane]      = f2bf(x0);
        xr[tk * XSTR + lane + 64] = f2bf(x1);
    }
    __syncthreads();

    // ---- GEMM: 6 m-tiles x 4 n-tiles x 4 k-steps (16x16x32), swapped operands
    const unsigned int* a32 = (const unsigned int*)((wave == 3) ? xr : xn);
    for (int mt = 0; mt < 6; ++mt) {
        bf16x8 af[4];
#pragma unroll
        for (int ks = 0; ks < 4; ++ks) {
            int adw = (mt * 16 + jl) * (XSTR / 2) + ks * 16 + g * 4;
            union { unsigned int u[4]; bf16x8 v; } cv;
            cv.u[0] = a32[adw]; cv.u[1] = a32[adw + 1];
            cv.u[2] = a32[adw + 2]; cv.u[3] = a32[adw + 3];
            af[ks] = cv.v;
        }
#pragma unroll
        for (int t = 0; t < 4; ++t) {
            int nt = wave * 4 + t;
            f32x4 acc = {0.f, 0.f, 0.f, 0.f};
#pragma unroll
            for (int ks = 0; ks < 4; ++ks) acc = MFMA32(wfrag[t][ks], af[ks], acc);
            // D[c][token]: row (g*4+r) = feature dim, col (jl) = token
            int mat = nt >> 2, hh = nt & 3;
            int token = q4 * 96 + mt * 16 + jl;
            long base = (((long)b * NHEADS + hh) * LSEQ + token) * HDIM + g * 4;
            if (mat == 3) {
                float4 gb = gb4[t];
                float v0 = fsigm(acc[0] + gb.x), v1 = fsigm(acc[1] + gb.y);
                float v2 = fsigm(acc[2] + gb.z), v3 = fsigm(acc[3] + gb.w);
                uint2 pk = { pkbf(v0, v1), pkbf(v2, v3) };
                *(uint2*)(gws + base) = pk;
            } else {
                unsigned short* outp = (mat == 0) ? qws : (mat == 1) ? kws : vws;
                uint2 pk = { pkbf(acc[0], acc[1]), pkbf(acc[2], acc[3]) };
                *(uint2*)(outp + base) = pk;
            }
        }
    }
}

// ================= attention core: S=QK^T, softmax over j, O=P^T V, gate ===
#if HAVE_MFMA16
typedef bf16x4 sfrag_t;
#define SMFMA(A,B,C) __builtin_amdgcn_mfma_f32_16x16x16bf16_1k(A,B,C,0,0,0)
__device__ __forceinline__ sfrag_t ldfrag(const unsigned int* b32, int row, int g) {
    union { unsigned int u[2]; bf16x4 v; } c;
    const unsigned int* p = b32 + row * 12 + g * 2;
    c.u[0] = p[0]; c.u[1] = p[1];
    return c.v;
}
#else
typedef bf16x8 sfrag_t;
#define SMFMA(A,B,C) MFMA32(A,B,C)
__device__ __forceinline__ sfrag_t ldfrag(const unsigned int* b32, int row, int g) {
    union { unsigned int u[4]; bf16x8 v; } c;
    if (g < 2) {
        uint4 x = *(const uint4*)(b32 + row * 12 + g * 4);
        c.u[0] = x.x; c.u[1] = x.y; c.u[2] = x.z; c.u[3] = x.w;
    } else {
        c.u[0] = c.u[1] = c.u[2] = c.u[3] = 0;
    }
    return c.v;
}
#endif

__global__ __launch_bounds__(256, 2) void attn_core_kernel(
    const unsigned short* __restrict__ qws, const unsigned short* __restrict__ kws,
    const unsigned short* __restrict__ vws, const unsigned short* __restrict__ gws,
    float* __restrict__ attn_out)
{
    const int b = blockIdx.x, h = blockIdx.y;
    const int tid = threadIdx.x, wave = tid >> 6, lane = tid & 63;
    const int jl  = lane & 15, g = lane >> 4;

    __shared__ __align__(16) unsigned short qs[LSEQ * 24];   // 18432 B
    __shared__ __align__(16) unsigned short ks[LSEQ * 24];   // 18432 B
    __shared__ __align__(16) unsigned short vs[LSEQ * 18];   // 13824 B
    __shared__ float linv[LSEQ];                             //  1536 B  (total 52224 -> 3 blocks/CU)

    const long goff = ((long)b * NHEADS + h) * (LSEQ * HDIM);

    // ---- stage q,k (stride 24), v (stride 18); gate stays in global (no reuse)
    {
        const uint4* gq = (const uint4*)(qws + goff);
        const uint4* gk = (const uint4*)(kws + goff);
        unsigned int* q32s = (unsigned int*)qs;
        unsigned int* k32s = (unsigned int*)ks;
        for (int e = tid; e < 768; e += 256) {
            int tk = e >> 1, hf = e & 1;
            *(uint4*)(q32s + tk * 12 + hf * 4) = gq[e];
            *(uint4*)(k32s + tk * 12 + hf * 4) = gk[e];
        }
        const unsigned int* gv = (const unsigned int*)(vws + goff);
        unsigned int* v32 = (unsigned int*)vs;
        for (int e = tid; e < 3072; e += 256) {
            int tk = e >> 3, j = e & 7;
            v32[tk * 9 + j] = gv[e];
        }
    }
    __syncthreads();

    const unsigned int* q32 = (const unsigned int*)qs;
    const unsigned int* k32 = (const unsigned int*)ks;

    // own-tile frags (tile = wave*6 + t)
    sfrag_t Qo[6], Ko[6];
#pragma unroll
    for (int t = 0; t < 6; ++t) {
        Qo[t] = ldfrag(q32, (wave * 6 + t) * 16 + jl, g);
        Ko[t] = ldfrag(k32, (wave * 6 + t) * 16 + jl, g);
    }

    const f32x4 fz = {0.f, 0.f, 0.f, 0.f};

    // ---- pass 1: l_i = sum_j 2^(s'_ij); scores pre-scaled via q by 0.25*log2e
    for (int t = 0; t < 6; ++t) {
        float lsum = 0.f;
        for (int u = 0; u < 12; ++u) {
            sfrag_t c0 = ldfrag(k32, 32 * u + jl, g);
            sfrag_t c1 = ldfrag(k32, 32 * u + 16 + jl, g);
            f32x4 s0 = SMFMA(c0, Qo[t], fz);
            f32x4 s1 = SMFMA(c1, Qo[t], fz);
            float e0 = ex2(s0[0]) + ex2(s0[1]);
            float e1 = ex2(s0[2]) + ex2(s0[3]);
            float e2 = ex2(s1[0]) + ex2(s1[1]);
            float e3 = ex2(s1[2]) + ex2(s1[3]);
            lsum += (e0 + e1) + (e2 + e3);
        }
        lsum += __shfl_xor(lsum, 16, 64);
        lsum += __shfl_xor(lsum, 32, 64);
        if (lane < 16) linv[(wave * 6 + t) * 16 + jl] = 1.f / lsum;
    }
    __syncthreads();

    // ---- V-hat B-frags with the tau permutation: slot (g,jj) -> token
    bf16x8 VB8[12];
#pragma unroll
    for (int u = 0; u < 12; ++u) {
        union { unsigned int w[4]; bf16x8 v; } vv;
#pragma unroll
        for (int p = 0; p < 4; ++p) {
            int t0 = 32 * u + ((p < 2) ? (g * 4 + 2 * p) : (16 + g * 4 + 2 * (p - 2)));
            float a  = bf2f_s(vs[t0 * 18 + jl])       * linv[t0];
            float bb = bf2f_s(vs[(t0 + 1) * 18 + jl]) * linv[t0 + 1];
            vv.w[p] = pkbf(a, bb);
        }
        VB8[u] = vv.v;
    }

    // ---- pass 2 (swapped): O[d][j] so thread holds 4 consecutive d -> float4 store
    for (int t = 0; t < 6; ++t) {
        int jrow = (wave * 6 + t) * 16 + jl;
        // gate prefetch: 4 consecutive dims of this token (hide latency under u-loop)
        uint2 gpk = *(const uint2*)(gws + goff + (long)jrow * 16 + g * 4);

        f32x4 o = fz;
        for (int u = 0; u < 12; ++u) {
            sfrag_t c0 = ldfrag(q32, 32 * u + jl, g);
            sfrag_t c1 = ldfrag(q32, 32 * u + 16 + jl, g);
            f32x4 s0 = SMFMA(c0, Ko[t], fz);
            f32x4 s1 = SMFMA(c1, Ko[t], fz);
            union { unsigned int w[4]; bf16x8 v; } pf;
            pf.w[0] = pkbf(ex2(s0[0]), ex2(s0[1]));
            pf.w[1] = pkbf(ex2(s0[2]), ex2(s0[3]));
            pf.w[2] = pkbf(ex2(s1[0]), ex2(s1[1]));
            pf.w[3] = pkbf(ex2(s1[2]), ex2(s1[3]));
            o = MFMA32(VB8[u], pf.v, o);    // D[d][j]
        }
        float4 res;
        res.x = o[0] * bf2f_lo(gpk.x);
        res.y = o[1] * bf2f_hi(gpk.x);
        res.z = o[2] * bf2f_lo(gpk.y);
        res.w = o[3] * bf2f_hi(gpk.y);
        *(float4*)(attn_out + ((long)b * LSEQ + jrow) * 64 + h * HDIM + g * 4) = res;
    }
}

// ========== fin projection: out[t,c] = R[t,c] + bias[c] + sum_k A[t,k]*W[c,k] ==========
// Swapped operands: D[c][token] -> float4 residual loads + float4 stores.
template <int K, int NT>
__global__ __launch_bounds__(256, 2) void mproj_kernel(
    const float* __restrict__ A,
    const float* __restrict__ W, const float* __restrict__ Bv,
    const float* R, long rs0, long rs1,
    float* out, long os0, long os1)
{
    constexpr int KS = K / 32;        // MFMA k-steps
    constexpr int RS = K / 2 + 4;     // LDS row stride in dwords
    const int tid = threadIdx.x, wave = tid >> 6, lane = tid & 63;
    const int jl = lane & 15, g = lane >> 4;

    __shared__ __align__(16) unsigned int abuf[96 * RS];

    bf16x8 wfrag[NT][KS];
    float4 bias4[NT];
#pragma unroll
    for (int t = 0; t < NT; ++t) {
        int c = (wave * NT + t) * 16 + jl;
        const float* wr = W + (long)c * K;
        bias4[t] = *(const float4*)(Bv + (wave * NT + t) * 16 + g * 4);
#pragma unroll
        for (int ks = 0; ks < KS; ++ks) {
            int k0 = ks * 32 + g * 8;
            float4 w0 = *(const float4*)(wr + k0);
            float4 w1 = *(const float4*)(wr + k0 + 4);
            union { unsigned int u[4]; bf16x8 v; } f;
            f.u[0] = pkbf(w0.x, w0.y);
            f.u[1] = pkbf(w0.z, w0.w);
            f.u[2] = pkbf(w1.x, w1.y);
            f.u[3] = pkbf(w1.z, w1.w);
            wfrag[t][ks] = f.v;
        }
    }

    // ---- stage A as bf16 into LDS
    const long t0 = (long)blockIdx.x * 96;
    for (int e = tid; e < 96 * (K / 2); e += 256) {
        int row = e / (K / 2), cp = e % (K / 2);
        float2 a = *(const float2*)(A + t0 * K + 2 * e);
        abuf[row * RS + cp] = pkbf(a.x, a.y);
    }
    __syncthreads();

    const int i0 = blockIdx.x >> 2;
    const int j0b = (blockIdx.x & 3) * 96;

    for (int mt = 0; mt < 6; ++mt) {
        bf16x8 af[KS];
#pragma unroll
        for (int ks = 0; ks < KS; ++ks) {
            int adw = (mt * 16 + jl) * RS + ks * 16 + g * 4;
            uint4 x = *(const uint4*)(abuf + adw);
            union { unsigned int u[4]; bf16x8 v; } cv;
            cv.u[0] = x.x; cv.u[1] = x.y; cv.u[2] = x.z; cv.u[3] = x.w;
            af[ks] = cv.v;
        }
#pragma unroll
        for (int t = 0; t < NT; ++t) {
            f32x4 acc = {0.f, 0.f, 0.f, 0.f};
#pragma unroll
            for (int ks = 0; ks < KS; ++ks) acc = MFMA32(wfrag[t][ks], af[ks], acc);
            int tj = j0b + mt * 16 + jl;
            long cbase = (wave * NT + t) * 16 + g * 4;
            float4 rq = *(const float4*)(R + (long)i0 * rs0 + (long)tj * rs1 + cbase);
            float4 bq = bias4[t];
            float4 vv;
            vv.x = acc[0] + bq.x + rq.x;
            vv.y = acc[1] + bq.y + rq.y;
            vv.z = acc[2] + bq.z + rq.z;
            vv.w = acc[3] + bq.w + rq.w;
            *(float4*)(out + (long)i0 * os0 + (long)tj * os1 + cbase) = vv;
        }
    }
}

// ========== fused feed-forward: out = y + silu(silu(y)@W1.T+b1)@W2.T + b2 ==========
// Per block: 96 tokens. GEMM1 swapped (D[c][token]) -> bf16 h in LDS via uint2
// writes; GEMM2 swapped (D[co][token]) -> float4 residual + store.
__global__ __launch_bounds__(256, 2) void ff_fused_kernel(
    const float* __restrict__ Y,
    const float* __restrict__ W1, const float* __restrict__ B1,
    const float* __restrict__ W2, const float* __restrict__ B2,
    float* __restrict__ out)
{
    const int tid = threadIdx.x, wave = tid >> 6, lane = tid & 63;
    const int jl = lane & 15, g = lane >> 4;

    __shared__ __align__(16) unsigned int xs[96 * 68];    // 26112 B  silu(y) bf16
    __shared__ __align__(16) unsigned int hs[96 * 132];   // 50688 B  silu(h) bf16

    // ---- W1 frags: wave owns cols wave*64 + t*16 .. +15 (t=0..3), KS=4
    bf16x8 w1f[4][4];
    float4 b1q[4];
#pragma unroll
    for (int t = 0; t < 4; ++t) {
        int c = wave * 64 + t * 16 + jl;
        const float* wr = W1 + (long)c * 128;
        b1q[t] = *(const float4*)(B1 + wave * 64 + t * 16 + g * 4);
#pragma unroll
        for (int ks = 0; ks < 4; ++ks) {
            int k0 = ks * 32 + g * 8;
            float4 w0 = *(const float4*)(wr + k0);
            float4 w1 = *(const float4*)(wr + k0 + 4);
            union { unsigned int u[4]; bf16x8 v; } f;
            f.u[0] = pkbf(w0.x, w0.y);
            f.u[1] = pkbf(w0.z, w0.w);
            f.u[2] = pkbf(w1.x, w1.y);
            f.u[3] = pkbf(w1.z, w1.w);
            w1f[t][ks] = f.v;
        }
    }

    // ---- stage silu(Y) as bf16
    const long t0 = (long)blockIdx.x * 96;
    for (int e = tid; e < 96 * 64; e += 256) {
        int row = e >> 6, cp = e & 63;
        float2 a = *(const float2*)(Y + t0 * 128 + 2 * e);
        xs[row * 68 + cp] = pkbf(fsilu(a.x), fsilu(a.y));
    }
    __syncthreads();

    // ---- GEMM1 (swapped): h[c][token]; silu; bf16 -> hs
    for (int mt = 0; mt < 6; ++mt) {
        bf16x8 af[4];
#pragma unroll
        for (int ks = 0; ks < 4; ++ks) {
            int adw = (mt * 16 + jl) * 68 + ks * 16 + g * 4;
            uint4 x = *(const uint4*)(xs + adw);
            union { unsigned int u[4]; bf16x8 v; } cv;
            cv.u[0] = x.x; cv.u[1] = x.y; cv.u[2] = x.z; cv.u[3] = x.w;
            af[ks] = cv.v;
        }
#pragma unroll
        for (int t = 0; t < 4; ++t) {
            f32x4 acc = {0.f, 0.f, 0.f, 0.f};
#pragma unroll
            for (int ks = 0; ks < 4; ++ks) acc = MFMA32(w1f[t][ks], af[ks], acc);
            float4 bq = b1q[t];
            float h0 = fsilu(acc[0] + bq.x), h1 = fsilu(acc[1] + bq.y);
            float h2 = fsilu(acc[2] + bq.z), h3 = fsilu(acc[3] + bq.w);
            uint2 pk = { pkbf(h0, h1), pkbf(h2, h3) };
            *(uint2*)(hs + (mt * 16 + jl) * 132 + wave * 32 + t * 8 + g * 2) = pk;
        }
    }

    // ---- W2 frags loaded here: latency hides under the barrier wait
    bf16x8 w2f[2][8];
    float4 b2q[2];
#pragma unroll
    for (int t = 0; t < 2; ++t) {
        int co = wave * 32 + t * 16 + jl;
        const float* wr = W2 + (long)co * 256;
        b2q[t] = *(const float4*)(B2 + wave * 32 + t * 16 + g * 4);
#pragma unroll
        for (int ks = 0; ks < 8; ++ks) {
            int k0 = ks * 32 + g * 8;
            float4 w0 = *(const float4*)(wr + k0);
            float4 w1 = *(const float4*)(wr + k0 + 4);
            union { unsigned int u[4]; bf16x8 v; } f;
            f.u[0] = pkbf(w0.x, w0.y);
            f.u[1] = pkbf(w0.z, w0.w);
            f.u[2] = pkbf(w1.x, w1.y);
            f.u[3] = pkbf(w1.z, w1.w);
            w2f[t][ks] = f.v;
        }
    }
    __syncthreads();

    // ---- GEMM2 (swapped): out[co][token] + b2 + residual y
    const int i0 = blockIdx.x >> 2;
    const int j0b = (blockIdx.x & 3) * 96;

    for (int mt = 0; mt < 6; ++mt) {
        bf16x8 af[8];
#pragma unroll
        for (int ks = 0; ks < 8; ++ks) {
            int adw = (mt * 16 + jl) * 132 + ks * 16 + g * 4;
            uint4 x = *(const uint4*)(hs + adw);
            union { unsigned int u[4]; bf16x8 v; } cv;
            cv.u[0] = x.x; cv.u[1] = x.y; cv.u[2] = x.z; cv.u[3] = x.w;
            af[ks] = cv.v;
        }
#pragma unroll
        for (int t = 0; t < 2; ++t) {
            f32x4 acc = {0.f, 0.f, 0.f, 0.f};
#pragma unroll
            for (int ks = 0; ks < 8; ++ks) acc = MFMA32(w2f[t][ks], af[ks], acc);
            int tj = j0b + mt * 16 + jl;
            long cbase = wave * 32 + t * 16 + g * 4;
            long addr = (long)i0 * 49152 + (long)tj * 128 + cbase;
            float4 rq = *(const float4*)(Y + addr);
            float4 bq = b2q[t];
            float4 vv;
            vv.x = acc[0] + bq.x + rq.x;
            vv.y = acc[1] + bq.y + rq.y;
            vv.z = acc[2] + bq.z + rq.z;
            vv.w = acc[3] + bq.w + rq.w;
            *(float4*)(out + addr) = vv;
        }
    }
}

// ---------- launch ----------
extern "C" void kernel_launch(void* const* d_in, const int* in_sizes, int n_in,
                              void* d_out, int out_size, void* d_ws, size_t ws_size,
                              hipStream_t stream)
{
    const float* edge     = (const float*)d_in[0];
    const float* r_ln_g   = (const float*)d_in[1];
    const float* r_ln_b   = (const float*)d_in[2];
    const float* r_qkv_w  = (const float*)d_in[3];
    const float* r_gate_w = (const float*)d_in[4];
    const float* r_gate_b = (const float*)d_in[5];
    const float* r_fin_w  = (const float*)d_in[6];
    const float* r_fin_b  = (const float*)d_in[7];
    const float* c_ln_g   = (const float*)d_in[8];
    const float* c_ln_b   = (const float*)d_in[9];
    const float* c_qkv_w  = (const float*)d_in[10];
    const float* c_gate_w = (const float*)d_in[11];
    const float* c_gate_b = (const float*)d_in[12];
    const float* c_fin_w  = (const float*)d_in[13];
    const float* c_fin_b  = (const float*)d_in[14];
    const float* ff_w1    = (const float*)d_in[15];
    const float* ff_b1    = (const float*)d_in[16];
    const float* ff_w2    = (const float*)d_in[17];
    const float* ff_b2    = (const float*)d_in[18];

    char* ws = (char*)d_ws;
    unsigned short* qb = (unsigned short*)ws;
    unsigned short* kb = qb + 9437184;
    unsigned short* vb = qb + 2 * 9437184;
    unsigned short* gb = qb + 3 * 9437184;
    float* attn = (float*)(ws + 75497472);                      // 37,748,736 B
    float* y    = (float*)(ws + 75497472 + 37748736);           // 75,497,472 B

    const long LD = 49152; // 384*128

    // ---- row attention
    qkvg_kernel<<<dim3(LSEQ, 4), 256, 0, stream>>>(
        edge, LD, 128, r_ln_g, r_ln_b, r_qkv_w, r_gate_w, r_gate_b, qb, kb, vb, gb);
    attn_core_kernel<<<dim3(LSEQ, NHEADS), 256, 0, stream>>>(qb, kb, vb, gb, attn);
    mproj_kernel<64, 2><<<1536, 256, 0, stream>>>(
        attn, r_fin_w, r_fin_b, edge, LD, 128, y, LD, 128);

    // ---- column attention (x viewed transposed via strides)
    qkvg_kernel<<<dim3(LSEQ, 4), 256, 0, stream>>>(
        y, 128, LD, c_ln_g, c_ln_b, c_qkv_w, c_gate_w, c_gate_b, qb, kb, vb, gb);
    attn_core_kernel<<<dim3(LSEQ, NHEADS), 256, 0, stream>>>(qb, kb, vb, gb, attn);
    mproj_kernel<64, 2><<<1536, 256, 0, stream>>>(
        attn, c_fin_w, c_fin_b, y, 128, LD, y, 128, LD);

    // ---- fused feed-forward
    ff_fused_kernel<<<1536, 256, 0, stream>>>(
        y, ff_w1, ff_b1, ff_w2, ff_b2, (float*)d_out);
}